// Round 9
// baseline (762.225 us; speedup 1.0000x reference)
//
#include <hip/hip_runtime.h>
#include <hip/hip_bf16.h>

// ---------------------------------------------------------------------------
// StreamingQwenMoE round 9: fused-dequant routed GEMMs with staging moved OFF
// the serial path + pure-DMA shared GEMMs.
//   r8 measured: clean-DMA GEMM worth ~70us on gate+up (VALU staging was the
//   cost), but the 906 MB pre-dequant pass cost more than it saved.
//   New routed loop: issue(t+2) | compute(t) | storeB(t+1) | lgkm | vmcnt(12)
//   | barrier -- the cvt+ds_write of NEXT tile's B interleaves into compute's
//   MFMA issue gaps (no sched_barrier between them); double-buffered sB makes
//   the early write safe (barrier(t) proves tile t-1 readers are done).
//   Shared GEMMs: r8's k_gemm16 (both operands global_load_lds) + 50 MB
//   pre-cast of shared weights (cheap, measured structure).
// ws >= 270 MB confirmed (r8 big path ran). LDS 81920 exactly (2 blocks/CU).
// Verified carried: router/top8/dispatch, SwiGLU, C/D layout, XOR swizzle,
// bijective XCD swizzle, atomic-free pair-buffer combine.
// ---------------------------------------------------------------------------

#define TT   2048
#define DD   2048
#define DFF  768
#define DSH  2048
#define EE   32
#define KTOP 8
#define CAP  1024

typedef _Float16 half8  __attribute__((ext_vector_type(8)));
typedef _Float16 half4v __attribute__((ext_vector_type(4)));
typedef float    f32x4  __attribute__((ext_vector_type(4)));

// ---------------- init ------------------------------------------------------
__global__ __launch_bounds__(256) void k_init(int* __restrict__ cnt,
                                              int* __restrict__ slot_tok) {
  int i = blockIdx.x * 256 + threadIdx.x;
  if (i < EE * CAP) slot_tok[i] = 0;
  if (i < EE) cnt[i] = 0;
}

// ---------------- f32 -> f16 cast -------------------------------------------
__global__ __launch_bounds__(256) void k_cast(const float* __restrict__ in,
                                              _Float16* __restrict__ out) {
  int i = blockIdx.x * 256 + threadIdx.x;
  float4 v = ((const float4*)in)[i];
  half4v h = { (_Float16)v.x, (_Float16)v.y, (_Float16)v.z, (_Float16)v.w };
  ((half4v*)out)[i] = h;
}

// ---------------- router: logits, top8, renorm, dispatch --------------------
__global__ __launch_bounds__(64) void k_router(
    const float* __restrict__ x, const float* __restrict__ rw,
    const float* __restrict__ wshg,
    float* __restrict__ shg, int* __restrict__ cnt,
    int* __restrict__ slot_tok, float* __restrict__ slot_w,
    int* __restrict__ slot_pair, int* __restrict__ pair_pos) {
  int t = blockIdx.x;
  int lane = threadIdx.x;
  const float* xr = x + (size_t)t * DD;
  float xv[32];
#pragma unroll
  for (int j = 0; j < 32; ++j) xv[j] = xr[lane + j * 64];

  __shared__ float lg[EE];
  for (int e = 0; e < EE; ++e) {
    const float* we = rw + (size_t)e * DD;
    float s = 0.f;
#pragma unroll
    for (int j = 0; j < 32; ++j) s += xv[j] * we[lane + j * 64];
#pragma unroll
    for (int off = 32; off > 0; off >>= 1) s += __shfl_down(s, off);
    if (lane == 0) lg[e] = s;
  }
  {
    float s = 0.f;
#pragma unroll
    for (int j = 0; j < 32; ++j) s += xv[j] * wshg[lane + j * 64];
#pragma unroll
    for (int off = 32; off > 0; off >>= 1) s += __shfl_down(s, off);
    if (lane == 0) shg[t] = 1.f / (1.f + expf(-s));
  }
  if (lane == 0) {
    unsigned used = 0;
    int sel[KTOP];
    float val[KTOP];
    for (int k = 0; k < KTOP; ++k) {
      float bv = -1e30f; int bi = 0;
      for (int e = 0; e < EE; ++e)
        if (!((used >> e) & 1) && lg[e] > bv) { bv = lg[e]; bi = e; }
      used |= (1u << bi);
      sel[k] = bi; val[k] = bv;
    }
    float mx = val[0], sum = 0.f;
    for (int k = 0; k < KTOP; ++k) { val[k] = expf(val[k] - mx); sum += val[k]; }
    float inv = 1.f / sum;
    for (int k = 0; k < KTOP; ++k) {
      int e = sel[k];
      int pos = atomicAdd(&cnt[e], 1);
      pair_pos[t * KTOP + k] = pos;
      if (pos < CAP) {
        slot_tok[e * CAP + pos] = t;
        slot_w[e * CAP + pos] = val[k] * inv;
        slot_pair[e * CAP + pos] = t * KTOP + k;
      }
    }
  }
}

// ============ routed GEMM: fused dequant, overlapped storeB =================
// C = A (rows x K, f16) * (s*B)^T, B f32 [N,K] with 128x128 block scales.
// Loop: issue A(t+2),B(t+2) | compute(t) | storeB(t+1) | lgkm | vmcnt(12) |
// barrier.  storeB's cvt interleaves with compute's MFMA issue gaps.
// EPI: 0 = f16 OutH (SwiGLU, DUAL); 1 = f16 scatter w*val -> OutH[pair*DD].
template<bool DUAL, bool GATHER, int EPI, int NPB, int MBB, int KDIM>
__global__ __launch_bounds__(256, 2) void k_gemm(
    const _Float16* __restrict__ A,
    const float* __restrict__ B0f, const float* __restrict__ B1f,
    const float* __restrict__ S0, const float* __restrict__ S1,
    int sCols, int sStrideE,
    _Float16* __restrict__ OutH,
    int ldA, int ldOut,
    long long strideAE, long long strideBE, long long strideOE,
    const int* __restrict__ cnt,
    const int* __restrict__ slot_tok, const float* __restrict__ slot_w) {
  constexpr int BK = 64;
  constexpr int KT = KDIM / BK;              // 32 / 12 (even)
  constexpr int NF = DUAL ? 2 : 4;
  constexpr int BN = DUAL ? 64 : 128;
  constexpr int BCH = DUAL ? 4 : 8;

  // bijective XCD swizzle: all m-blocks of pair (n,e) adjacent on one XCD
  const int f = blockIdx.x;
  const int xcd = f & 7;
  const int t0 = f >> 3;
  const int mb = t0 % MBB;
  const int pp = t0 / MBB;
  const int p  = pp * 8 + xcd;               // (NPB*E) % 8 == 0
  const int nb = p % NPB;
  const int e  = p / NPB;

  int rows = cnt[e] > CAP ? CAP : cnt[e];
  const int rowBase = mb * 128;
  if (rowBase >= rows) return;
  const int nBase = nb * BN;

  const int tid = threadIdx.x;
  const int lane = tid & 63;
  const int wave = tid >> 6;
  const int wr = wave >> 1;
  const int wc = wave & 1;

  __shared__ __align__(16) _Float16 sA[3][8192];   // 48 KB
  __shared__ __align__(16) _Float16 sB[2][8192];   // 32 KB (total 81920 B)

  const _Float16* Ae = A + (GATHER ? 0 : (long long)e * strideAE);
  const float* B0e = B0f + (long long)e * strideBE;
  const float* B1e = DUAL ? (B1f + (long long)e * strideBE) : nullptr;
  const float* S0e = S0 + (long long)e * sStrideE;
  const float* S1e = DUAL ? (S1 + (long long)e * sStrideE) : nullptr;
  const int sRow = (nBase >> 7) * sCols;

  // A staging (global_load_lds): LDS dest linear, source col pre-swizzled
  int aByte[4];
#pragma unroll
  for (int i = 0; i < 4; ++i) {
    int c = tid + i * 256;
    int row = c >> 3;
    int colB = ((c & 7) << 4) ^ ((row & 7) << 4);
    int src = GATHER ? slot_tok[e * CAP + rowBase + row] : (rowBase + row);
    aByte[i] = src * (2 * ldA) + colB;
  }
  // B staging: reg->cvt->swizzled LDS write
  int bOff[BCH], wByte[BCH];
#pragma unroll
  for (int i = 0; i < BCH; ++i) {
    int c = tid + i * 256;
    int rn = c >> 4;
    int c4 = (c & 15) << 2;
    bOff[i] = (nBase + rn) * KDIM + c4;
    wByte[i] = ((rn << 7) + (c4 << 1)) ^ ((rn & 7) << 4);
  }

  f32x4 accG[4][NF];
  f32x4 accU[DUAL ? 4 : 1][NF];
#pragma unroll
  for (int m = 0; m < 4; ++m)
#pragma unroll
    for (int n = 0; n < NF; ++n) {
      accG[m][n] = (f32x4){0.f, 0.f, 0.f, 0.f};
      if constexpr (DUAL) accU[m][n] = (f32x4){0.f, 0.f, 0.f, 0.f};
    }

  auto stageA = [&](int kt, int buf) {       // 4 DMA
#pragma unroll
    for (int i = 0; i < 4; ++i) {
      __builtin_amdgcn_global_load_lds(
          (const __attribute__((address_space(1))) void*)
              ((const char*)Ae + aByte[i] + kt * (BK * 2)),
          (__attribute__((address_space(3))) void*)&sA[buf][(tid + i * 256) * 8],
          16, 0, 0);
    }
  };
  auto loadB = [&](int kt, float4 (&r0)[BCH], float4 (&r1)[BCH]) {  // 8 loads
    const int ko = kt * BK;
#pragma unroll
    for (int i = 0; i < BCH; ++i) r0[i] = *(const float4*)(B0e + bOff[i] + ko);
    if constexpr (DUAL) {
#pragma unroll
      for (int i = 0; i < BCH; ++i) r1[i] = *(const float4*)(B1e + bOff[i] + ko);
    }
  };
  auto storeB = [&](int kt, float4 (&r0)[BCH], float4 (&r1)[BCH]) {
    float s0 = S0e[sRow + (kt >> 1)];        // uniform -> scalar load, hoistable
    float s1 = DUAL ? S1e[sRow + (kt >> 1)] : 0.f;
    char* base = (char*)&sB[kt & 1][0];
#pragma unroll
    for (int i = 0; i < BCH; ++i) {
      half4v h = { (_Float16)(r0[i].x * s0), (_Float16)(r0[i].y * s0),
                   (_Float16)(r0[i].z * s0), (_Float16)(r0[i].w * s0) };
      *(half4v*)(base + wByte[i]) = h;
      if constexpr (DUAL) {
        half4v h1 = { (_Float16)(r1[i].x * s1), (_Float16)(r1[i].y * s1),
                      (_Float16)(r1[i].z * s1), (_Float16)(r1[i].w * s1) };
        *(half4v*)(base + 8192 + wByte[i]) = h1;
      }
    }
  };
  auto computeTile = [&](int ia, int ib) {
    const char* pA = (const char*)&sA[ia][0];
    const char* pB = (const char*)&sB[ib][0];
#pragma unroll
    for (int kk = 0; kk < 2; ++kk) {
      const int koff = kk * 32 + (lane >> 4) * 8;
      half8 a[4];
#pragma unroll
      for (int m = 0; m < 4; ++m) {
        int r = wr * 64 + m * 16 + (lane & 15);
        int byt = ((r << 7) + (koff << 1)) ^ ((r & 7) << 4);
        a[m] = *(const half8*)(pA + byt);
      }
      if constexpr (DUAL) {
        half8 bg[2], bu[2];
#pragma unroll
        for (int n = 0; n < 2; ++n) {
          int rn = wc * 32 + n * 16 + (lane & 15);
          int byt = ((rn << 7) + (koff << 1)) ^ ((rn & 7) << 4);
          bg[n] = *(const half8*)(pB + byt);
          bu[n] = *(const half8*)(pB + 8192 + byt);
        }
#pragma unroll
        for (int m = 0; m < 4; ++m)
#pragma unroll
          for (int n = 0; n < 2; ++n) {
            accG[m][n] = __builtin_amdgcn_mfma_f32_16x16x32_f16(a[m], bg[n], accG[m][n], 0, 0, 0);
            accU[m][n] = __builtin_amdgcn_mfma_f32_16x16x32_f16(a[m], bu[n], accU[m][n], 0, 0, 0);
          }
      } else {
        half8 b[4];
#pragma unroll
        for (int n = 0; n < 4; ++n) {
          int rn = wc * 64 + n * 16 + (lane & 15);
          int byt = ((rn << 7) + (koff << 1)) ^ ((rn & 7) << 4);
          b[n] = *(const half8*)(pB + byt);
        }
#pragma unroll
        for (int m = 0; m < 4; ++m)
#pragma unroll
          for (int n = 0; n < 4; ++n)
            accG[m][n] = __builtin_amdgcn_mfma_f32_16x16x32_f16(a[m], b[n], accG[m][n], 0, 0, 0);
      }
    }
  };

  // even/odd named B register sets (rule #20)
  float4 rbE0[BCH], rbE1[BCH], rbO0[BCH], rbO1[BCH];

  // prologue: B(0)->E, B(1)->O, A(0), A(1); convert B(0); clean barrier
  loadB(0, rbE0, rbE1);
  loadB(1, rbO0, rbO1);
  stageA(0, 0);
  stageA(1, 1);
  __builtin_amdgcn_sched_barrier(0);
  storeB(0, rbE0, rbE1);                     // compiler waits B(0) regs
  asm volatile("s_waitcnt lgkmcnt(0)" ::: "memory");
  asm volatile("s_waitcnt vmcnt(4)" ::: "memory");   // A(0) landed (A(1) newer)
  __builtin_amdgcn_s_barrier();
  __builtin_amdgcn_sched_barrier(0);

  int bufC = 0, bufW = 2;
  for (int kt = 0; kt < KT; ++kt) {
    // issue next-next tile first (prefetch depth 2)
    if (kt + 2 < KT) {
      stageA(kt + 2, bufW);
      if (kt & 1) loadB(kt + 2, rbO0, rbO1);   // set consumed by storeB(kt)
      else        loadB(kt + 2, rbE0, rbE1);
      __builtin_amdgcn_sched_barrier(0);
    }
    // compute current tile; next tile's staging interleaves into MFMA gaps
    computeTile(bufC, kt & 1);
    if (kt + 1 < KT) {
      if (kt & 1) storeB(kt + 1, rbE0, rbE1);
      else        storeB(kt + 1, rbO0, rbO1);
    }
    asm volatile("s_waitcnt lgkmcnt(0)" ::: "memory");
    if (kt + 2 < KT) { asm volatile("s_waitcnt vmcnt(12)" ::: "memory"); }
    else             { asm volatile("s_waitcnt vmcnt(0)"  ::: "memory"); }
    __builtin_amdgcn_s_barrier();
    __builtin_amdgcn_sched_barrier(0);
    bufC = (bufC == 2) ? 0 : bufC + 1;
    bufW = (bufW == 2) ? 0 : bufW + 1;
  }

  // epilogue; C/D layout: col = lane&15, row = (lane>>4)*4 + i (verified)
#pragma unroll
  for (int m = 0; m < 4; ++m) {
#pragma unroll
    for (int i = 0; i < 4; ++i) {
      int row = rowBase + wr * 64 + m * 16 + (lane >> 4) * 4 + i;
      if (row < rows) {
        if constexpr (EPI == 1) {
          int pair = slot_tok[e * CAP + row];
          float w = slot_w[e * CAP + row];
#pragma unroll
          for (int n = 0; n < NF; ++n) {
            int col = nBase + wc * 64 + n * 16 + (lane & 15);
            OutH[(long long)pair * DD + col] = (_Float16)(w * accG[m][n][i]);
          }
        } else {
          long long outBase = (long long)e * strideOE;
#pragma unroll
          for (int n = 0; n < NF; ++n) {
            int col = nBase + (DUAL ? wc * 32 : wc * 64) + n * 16 + (lane & 15);
            long long o = outBase + (long long)row * ldOut + col;
            if constexpr (DUAL) {
              float gv = accG[m][n][i];
              float uv = accU[m][n][i];
              OutH[o] = (_Float16)((gv / (1.f + __expf(-gv))) * uv);
            } else {
              OutH[o] = (_Float16)accG[m][n][i];
            }
          }
        }
      }
    }
  }
}

// ============ shared GEMM: pure DMA both operands (r8-verified) =============
// EPI: 0 = f16 OutH (SwiGLU if DUAL); 2 = OutF[row] += shg[row]*val.
template<bool DUAL, int EPI, int NPB, int MBB, int KDIM>
__global__ __launch_bounds__(256, 2) void k_gemm16(
    const _Float16* __restrict__ A,
    const _Float16* __restrict__ B0h, const _Float16* __restrict__ B1h,
    _Float16* __restrict__ OutH, float* __restrict__ OutF,
    const float* __restrict__ shg,
    int ldA, int ldOut, int rowsConst) {
  constexpr int BK = 64;
  constexpr int KT = KDIM / BK;
  constexpr int NF = DUAL ? 2 : 4;
  constexpr int BN = DUAL ? 64 : 128;

  const int f = blockIdx.x;
  const int xcd = f & 7;
  const int t0 = f >> 3;
  const int mb = t0 % MBB;
  const int pp = t0 / MBB;
  const int p  = pp * 8 + xcd;
  const int nb = p % NPB;

  int rows = rowsConst;
  const int rowBase = mb * 128;
  if (rowBase >= rows) return;
  const int nBase = nb * BN;

  const int tid = threadIdx.x;
  const int lane = tid & 63;
  const int wave = tid >> 6;
  const int wr = wave >> 1;
  const int wc = wave & 1;

  __shared__ __align__(16) _Float16 sA[3][8192];
  __shared__ __align__(16) _Float16 sB[2][8192];

  int aByte[4];
#pragma unroll
  for (int i = 0; i < 4; ++i) {
    int c = tid + i * 256;
    int row = c >> 3;
    int colB = ((c & 7) << 4) ^ ((row & 7) << 4);
    aByte[i] = (rowBase + row) * (2 * ldA) + colB;
  }
  int bByte[4];
#pragma unroll
  for (int i = 0; i < 4; ++i) {
    int c = tid + i * 256;
    int rn = DUAL ? ((c & 511) >> 3) : (c >> 3);
    int colB = ((c & 7) << 4) ^ ((rn & 7) << 4);
    bByte[i] = (nBase + rn) * (2 * KDIM) + colB;
  }

  f32x4 accG[4][NF];
  f32x4 accU[DUAL ? 4 : 1][NF];
#pragma unroll
  for (int m = 0; m < 4; ++m)
#pragma unroll
    for (int n = 0; n < NF; ++n) {
      accG[m][n] = (f32x4){0.f, 0.f, 0.f, 0.f};
      if constexpr (DUAL) accU[m][n] = (f32x4){0.f, 0.f, 0.f, 0.f};
    }

  auto stageA = [&](int kt, int buf) {
#pragma unroll
    for (int i = 0; i < 4; ++i) {
      __builtin_amdgcn_global_load_lds(
          (const __attribute__((address_space(1))) void*)
              ((const char*)A + aByte[i] + kt * 128),
          (__attribute__((address_space(3))) void*)&sA[buf][(tid + i * 256) * 8],
          16, 0, 0);
    }
  };
  auto stageB = [&](int kt, int buf) {
#pragma unroll
    for (int i = 0; i < 4; ++i) {
      const _Float16* src = (DUAL && i >= 2) ? B1h : B0h;
      __builtin_amdgcn_global_load_lds(
          (const __attribute__((address_space(1))) void*)
              ((const char*)src + bByte[i] + kt * 128),
          (__attribute__((address_space(3))) void*)&sB[buf][(tid + i * 256) * 8],
          16, 0, 0);
    }
  };
  auto computeTile = [&](int ia, int ib) {
    const char* pA = (const char*)&sA[ia][0];
    const char* pB = (const char*)&sB[ib][0];
#pragma unroll
    for (int kk = 0; kk < 2; ++kk) {
      const int koff = kk * 32 + (lane >> 4) * 8;
      half8 a[4];
#pragma unroll
      for (int m = 0; m < 4; ++m) {
        int r = wr * 64 + m * 16 + (lane & 15);
        int byt = ((r << 7) + (koff << 1)) ^ ((r & 7) << 4);
        a[m] = *(const half8*)(pA + byt);
      }
      if constexpr (DUAL) {
        half8 bg[2], bu[2];
#pragma unroll
        for (int n = 0; n < 2; ++n) {
          int rn = wc * 32 + n * 16 + (lane & 15);
          int byt = ((rn << 7) + (koff << 1)) ^ ((rn & 7) << 4);
          bg[n] = *(const half8*)(pB + byt);
          bu[n] = *(const half8*)(pB + 8192 + byt);
        }
#pragma unroll
        for (int m = 0; m < 4; ++m)
#pragma unroll
          for (int n = 0; n < 2; ++n) {
            accG[m][n] = __builtin_amdgcn_mfma_f32_16x16x32_f16(a[m], bg[n], accG[m][n], 0, 0, 0);
            accU[m][n] = __builtin_amdgcn_mfma_f32_16x16x32_f16(a[m], bu[n], accU[m][n], 0, 0, 0);
          }
      } else {
        half8 b[4];
#pragma unroll
        for (int n = 0; n < 4; ++n) {
          int rn = wc * 64 + n * 16 + (lane & 15);
          int byt = ((rn << 7) + (koff << 1)) ^ ((rn & 7) << 4);
          b[n] = *(const half8*)(pB + byt);
        }
#pragma unroll
        for (int m = 0; m < 4; ++m)
#pragma unroll
          for (int n = 0; n < 4; ++n)
            accG[m][n] = __builtin_amdgcn_mfma_f32_16x16x32_f16(a[m], b[n], accG[m][n], 0, 0, 0);
      }
    }
  };

  stageB(0, 0);
  __builtin_amdgcn_sched_barrier(0);
  stageA(0, 0);
  __builtin_amdgcn_sched_barrier(0);
  stageA(1, 1);
  __builtin_amdgcn_sched_barrier(0);

  int bufC = 0, bufW = 2;
  for (int kt = 0; kt < KT; ++kt) {
    asm volatile("s_waitcnt lgkmcnt(0)" ::: "memory");
    if (kt + 1 < KT) { asm volatile("s_waitcnt vmcnt(4)" ::: "memory"); }
    else             { asm volatile("s_waitcnt vmcnt(0)" ::: "memory"); }
    __builtin_amdgcn_sched_barrier(0);
    __builtin_amdgcn_s_barrier();
    __builtin_amdgcn_sched_barrier(0);
    if (kt + 1 < KT) stageB(kt + 1, (kt + 1) & 1);
    if (kt + 2 < KT) stageA(kt + 2, bufW);
    __builtin_amdgcn_sched_barrier(0);
    computeTile(bufC, kt & 1);
    bufC = (bufC == 2) ? 0 : bufC + 1;
    bufW = (bufW == 2) ? 0 : bufW + 1;
  }

#pragma unroll
  for (int m = 0; m < 4; ++m) {
#pragma unroll
    for (int i = 0; i < 4; ++i) {
      int row = rowBase + wr * 64 + m * 16 + (lane >> 4) * 4 + i;
      if (row < rows) {
        if constexpr (EPI == 2) {
          float g = shg[row];
#pragma unroll
          for (int n = 0; n < NF; ++n) {
            int col = nBase + wc * 64 + n * 16 + (lane & 15);
            OutF[(long long)row * DD + col] += g * accG[m][n][i];
          }
        } else {
#pragma unroll
          for (int n = 0; n < NF; ++n) {
            int col = nBase + (DUAL ? wc * 32 : wc * 64) + n * 16 + (lane & 15);
            long long o = (long long)row * ldOut + col;
            if constexpr (DUAL) {
              float gv = accG[m][n][i];
              float uv = accU[m][n][i];
              OutH[o] = (_Float16)((gv / (1.f + __expf(-gv))) * uv);
            } else {
              OutH[o] = (_Float16)accG[m][n][i];
            }
          }
        }
      }
    }
  }
}

// ---------------- combine: out[t] = sum_k (pos<CAP) Yp[t*8+k] ----------------
__global__ __launch_bounds__(256) void k_combine(
    const _Float16* __restrict__ Yp, const int* __restrict__ pair_pos,
    float* __restrict__ out) {
  int t = blockIdx.x;
  int col = threadIdx.x * 8;
  float acc[8] = {0.f, 0.f, 0.f, 0.f, 0.f, 0.f, 0.f, 0.f};
#pragma unroll
  for (int k = 0; k < KTOP; ++k) {
    if (pair_pos[t * KTOP + k] < CAP) {
      half8 y = *(const half8*)&Yp[((size_t)t * KTOP + k) * DD + col];
#pragma unroll
      for (int j = 0; j < 8; ++j) acc[j] += (float)y[j];
    }
  }
  float4 o0 = {acc[0], acc[1], acc[2], acc[3]};
  float4 o1 = {acc[4], acc[5], acc[6], acc[7]};
  *(float4*)&out[(size_t)t * DD + col] = o0;
  *(float4*)&out[(size_t)t * DD + col + 4] = o1;
}

// ---------------------------------------------------------------------------
extern "C" void kernel_launch(void* const* d_in, const int* in_sizes, int n_in,
                              void* d_out, int out_size, void* d_ws, size_t ws_size,
                              hipStream_t stream) {
  (void)in_sizes; (void)n_in; (void)out_size; (void)ws_size;
  const float* x    = (const float*)d_in[0];
  const float* rw   = (const float*)d_in[1];
  const float* wg   = (const float*)d_in[2];
  const float* sg   = (const float*)d_in[3];
  const float* wu   = (const float*)d_in[4];
  const float* su   = (const float*)d_in[5];
  const float* wd   = (const float*)d_in[6];
  const float* sd   = (const float*)d_in[7];
  const float* wsg  = (const float*)d_in[8];
  const float* wsu  = (const float*)d_in[9];
  const float* wsd  = (const float*)d_in[10];
  const float* wshg = (const float*)d_in[11];
  float* out = (float*)d_out;

  // workspace (~195 MB; ws >= 270 MB confirmed in r8)
  char* p = (char*)d_ws;
  auto alloc = [&](size_t bytes) {
    char* r = p;
    p += (bytes + 255) & ~(size_t)255;
    return r;
  };
  _Float16* x_h   = (_Float16*)alloc((size_t)TT * DD * 2);          //  8.4 MB
  _Float16* H     = (_Float16*)alloc((size_t)EE * CAP * DFF * 2);   // 50.3 MB
  _Float16* Hsh   = (_Float16*)alloc((size_t)TT * DSH * 2);         //  8.4 MB
  _Float16* Yp    = (_Float16*)alloc((size_t)TT * KTOP * DD * 2);   // 67.1 MB
  _Float16* wsg_h = (_Float16*)alloc((size_t)DSH * DD * 2);         //  8.4 MB
  _Float16* wsu_h = (_Float16*)alloc((size_t)DSH * DD * 2);         //  8.4 MB
  _Float16* wsd_h = (_Float16*)alloc((size_t)DD * DSH * 2);         //  8.4 MB
  float* shg      = (float*)alloc((size_t)TT * 4);
  int* cnt        = (int*)alloc((size_t)EE * 4);
  int* slot_tok   = (int*)alloc((size_t)EE * CAP * 4);
  float* slot_w   = (float*)alloc((size_t)EE * CAP * 4);
  int* slot_pair  = (int*)alloc((size_t)EE * CAP * 4);
  int* pair_pos   = (int*)alloc((size_t)TT * KTOP * 4);

  k_init<<<(EE * CAP + 255) / 256, 256, 0, stream>>>(cnt, slot_tok);
  k_cast<<<(TT * DD / 4) / 256, 256, 0, stream>>>(x, x_h);
  k_cast<<<(DSH * DD / 4) / 256, 256, 0, stream>>>(wsg, wsg_h);
  k_cast<<<(DSH * DD / 4) / 256, 256, 0, stream>>>(wsu, wsu_h);
  k_cast<<<(DD * DSH / 4) / 256, 256, 0, stream>>>(wsd, wsd_h);
  k_router<<<TT, 64, 0, stream>>>(x, rw, wshg, shg, cnt, slot_tok, slot_w,
                                  slot_pair, pair_pos);

  // routed gate+up (fused dequant, overlapped staging): NP=12, MB=8, E=32
  k_gemm<true, true, 0, 12, 8, DD><<<3072, 256, 0, stream>>>(
      x_h, wg, wu, sg, su, DD / 128, (DFF / 128) * (DD / 128),
      H, DD, DFF,
      0LL, (long long)DFF * DD, (long long)CAP * DFF,
      cnt, slot_tok, nullptr);

  // routed down -> Yp (fused dequant; pair map via slot_tok arg): NP=16, MB=8
  k_gemm<false, false, 1, 16, 8, DFF><<<4096, 256, 0, stream>>>(
      H, wd, wd, sd, sd, DFF / 128, (DD / 128) * (DFF / 128),
      Yp, DFF, DD,
      (long long)CAP * DFF, (long long)DD * DFF, 0LL,
      cnt, slot_pair, slot_w);

  k_combine<<<TT, 256, 0, stream>>>(Yp, pair_pos, out);

  // shared gate+up (pure DMA): NP=32, MB=16
  k_gemm16<true, 0, 32, 16, DD><<<512, 256, 0, stream>>>(
      x_h, wsg_h, wsu_h, Hsh, nullptr, nullptr,
      DD, DSH, TT);

  // shared down (out += shg*val, runs last): NP=16, MB=16
  k_gemm16<false, 2, 16, 16, DSH><<<256, 256, 0, stream>>>(
      Hsh, wsd_h, wsd_h, nullptr, out, shg,
      DSH, DD, TT);
}

// Round 10
// 704.412 us; speedup vs baseline: 1.0821x; 1.0821x over previous
//
#include <hip/hip_runtime.h>
#include <hip/hip_bf16.h>

// ---------------------------------------------------------------------------
// StreamingQwenMoE round 10: co-scheduled independent work (fill the idle GPU).
//   MEGA-A (4096 blocks): [0,3072) routed gate+up (r7 fused-dequant loop,
//     VERBATIM) | [3072,3584) shared gate+up (r8 clean-DMA loop, pre-cast
//     weights) | [3584,4096) wd dequant grid-stride stream (f32*scale->f16).
//   MEGA-B (4352 blocks): [0,4096) routed down CLEAN-DMA f16 (r8-measured
//     -VALU win, dequant cost hidden in MEGA-A) | [4096,4352) shared down
//     -> Ysh (clean).
//   combine2: out = sum_k keep*Yp[t*8+k] + shg[t]*Ysh[t]  (overwrites out).
// Measured facts driving this: all GEMM dispatches at ~16% occupancy and
// 14-16% HBM (machine idle); r8 clean-DMA worth ~70us on gu-class loops;
// r9 overlap trick regressed (reverted); LDS must stay <=81920.
// ws ~261 MB (Ysh aliases dead wsg_h); ws>=269MB confirmed in r8.
// ---------------------------------------------------------------------------

#define TT   2048
#define DD   2048
#define DFF  768
#define DSH  2048
#define EE   32
#define KTOP 8
#define CAP  1024

typedef _Float16 half8  __attribute__((ext_vector_type(8)));
typedef _Float16 half4v __attribute__((ext_vector_type(4)));
typedef float    f32x4  __attribute__((ext_vector_type(4)));

// ---------------- init ------------------------------------------------------
__global__ __launch_bounds__(256) void k_init(int* __restrict__ cnt,
                                              int* __restrict__ slot_tok) {
  int i = blockIdx.x * 256 + threadIdx.x;
  if (i < EE * CAP) slot_tok[i] = 0;
  if (i < EE) cnt[i] = 0;
}

// ---------------- f32 -> f16 cast -------------------------------------------
__global__ __launch_bounds__(256) void k_cast(const float* __restrict__ in,
                                              _Float16* __restrict__ out) {
  int i = blockIdx.x * 256 + threadIdx.x;
  float4 v = ((const float4*)in)[i];
  half4v h = { (_Float16)v.x, (_Float16)v.y, (_Float16)v.z, (_Float16)v.w };
  ((half4v*)out)[i] = h;
}

// ---------------- router: logits, top8, renorm, dispatch --------------------
__global__ __launch_bounds__(64) void k_router(
    const float* __restrict__ x, const float* __restrict__ rw,
    const float* __restrict__ wshg,
    float* __restrict__ shg, int* __restrict__ cnt,
    int* __restrict__ slot_tok, float* __restrict__ slot_w,
    int* __restrict__ slot_pair, int* __restrict__ pair_pos) {
  int t = blockIdx.x;
  int lane = threadIdx.x;
  const float* xr = x + (size_t)t * DD;
  float xv[32];
#pragma unroll
  for (int j = 0; j < 32; ++j) xv[j] = xr[lane + j * 64];

  __shared__ float lg[EE];
  for (int e = 0; e < EE; ++e) {
    const float* we = rw + (size_t)e * DD;
    float s = 0.f;
#pragma unroll
    for (int j = 0; j < 32; ++j) s += xv[j] * we[lane + j * 64];
#pragma unroll
    for (int off = 32; off > 0; off >>= 1) s += __shfl_down(s, off);
    if (lane == 0) lg[e] = s;
  }
  {
    float s = 0.f;
#pragma unroll
    for (int j = 0; j < 32; ++j) s += xv[j] * wshg[lane + j * 64];
#pragma unroll
    for (int off = 32; off > 0; off >>= 1) s += __shfl_down(s, off);
    if (lane == 0) shg[t] = 1.f / (1.f + expf(-s));
  }
  if (lane == 0) {
    unsigned used = 0;
    int sel[KTOP];
    float val[KTOP];
    for (int k = 0; k < KTOP; ++k) {
      float bv = -1e30f; int bi = 0;
      for (int e = 0; e < EE; ++e)
        if (!((used >> e) & 1) && lg[e] > bv) { bv = lg[e]; bi = e; }
      used |= (1u << bi);
      sel[k] = bi; val[k] = bv;
    }
    float mx = val[0], sum = 0.f;
    for (int k = 0; k < KTOP; ++k) { val[k] = expf(val[k] - mx); sum += val[k]; }
    float inv = 1.f / sum;
    for (int k = 0; k < KTOP; ++k) {
      int e = sel[k];
      int pos = atomicAdd(&cnt[e], 1);
      pair_pos[t * KTOP + k] = pos;
      if (pos < CAP) {
        slot_tok[e * CAP + pos] = t;
        slot_w[e * CAP + pos] = val[k] * inv;
        slot_pair[e * CAP + pos] = t * KTOP + k;
      }
    }
  }
}

// ===================== MEGA-A ==============================================
// [0,3072)  routed gate+up, fused dequant (r7 loop verbatim)  -> H
// [3072,3584) shared gate+up, clean DMA (r8 loop)             -> Hsh
// [3584,4096) wd dequant stream (f32*scale -> f16)            -> wd_h
__global__ __launch_bounds__(256, 2) void k_megaA(
    const _Float16* __restrict__ x_h,
    const float* __restrict__ wg, const float* __restrict__ wu,
    const float* __restrict__ sg, const float* __restrict__ su,
    _Float16* __restrict__ H,
    const int* __restrict__ cnt, const int* __restrict__ slot_tok,
    const _Float16* __restrict__ wsg_h, const _Float16* __restrict__ wsu_h,
    _Float16* __restrict__ Hsh,
    const float* __restrict__ wd, const float* __restrict__ sd,
    _Float16* __restrict__ wd_h) {
  __shared__ __align__(16) _Float16 sA[3][8192];   // 48 KB
  __shared__ __align__(16) _Float16 sB[2][8192];   // 32 KB (total 81920 B)

  const int tid = threadIdx.x;
  const int bid = blockIdx.x;

  if (bid >= 3584) {
    // ---------------- region 2: wd dequant stream --------------------------
    const long long tot4 = (long long)EE * DD * DFF / 4;   // 12,582,912
    long long idx = (long long)(bid - 3584) * 256 + tid;
    for (; idx < tot4; idx += 512LL * 256) {
      long long b = idx * 4;
      int e = (int)(b / ((long long)DD * DFF));
      int rem = (int)(b - (long long)e * DD * DFF);
      int r = rem / DFF;
      int c = rem - r * DFF;
      float sc = sd[e * ((DD / 128) * (DFF / 128)) + (r >> 7) * (DFF / 128) + (c >> 7)];
      float4 v = ((const float4*)wd)[idx];
      half4v h = { (_Float16)(v.x * sc), (_Float16)(v.y * sc),
                   (_Float16)(v.z * sc), (_Float16)(v.w * sc) };
      ((half4v*)wd_h)[idx] = h;
    }
    return;
  }

  const int lane = tid & 63;
  const int wave = tid >> 6;
  const int wr = wave >> 1;
  const int wc = wave & 1;

  if (bid >= 3072) {
    // ---------------- region 1: shared gate+up, clean DMA (r8 loop) --------
    constexpr int KT = DD / 64;               // 32
    const int f = bid - 3072;                 // [0,512)
    const int xcd = f & 7;
    const int t0 = f >> 3;
    const int mb = t0 % 16;
    const int pp = t0 / 16;
    const int p  = pp * 8 + xcd;              // [0,32)
    const int nb = p % 32;
    const int rowBase = mb * 128;
    const int nBase = nb * 64;

    int aByte[4];
#pragma unroll
    for (int i = 0; i < 4; ++i) {
      int c = tid + i * 256;
      int row = c >> 3;
      int colB = ((c & 7) << 4) ^ ((row & 7) << 4);
      aByte[i] = (rowBase + row) * (2 * DD) + colB;
    }
    int bByte[4];
#pragma unroll
    for (int i = 0; i < 4; ++i) {
      int c = tid + i * 256;
      int rn = (c & 511) >> 3;                // [0,64)
      int colB = ((c & 7) << 4) ^ ((rn & 7) << 4);
      bByte[i] = (nBase + rn) * (2 * DD) + colB;
    }

    f32x4 accG[4][2], accU[4][2];
#pragma unroll
    for (int m = 0; m < 4; ++m)
#pragma unroll
      for (int n = 0; n < 2; ++n) {
        accG[m][n] = (f32x4){0.f, 0.f, 0.f, 0.f};
        accU[m][n] = (f32x4){0.f, 0.f, 0.f, 0.f};
      }

    auto stageA = [&](int kt, int buf) {
#pragma unroll
      for (int i = 0; i < 4; ++i) {
        __builtin_amdgcn_global_load_lds(
            (const __attribute__((address_space(1))) void*)
                ((const char*)x_h + aByte[i] + kt * 128),
            (__attribute__((address_space(3))) void*)&sA[buf][(tid + i * 256) * 8],
            16, 0, 0);
      }
    };
    auto stageB = [&](int kt, int buf) {
#pragma unroll
      for (int i = 0; i < 4; ++i) {
        const _Float16* src = (i >= 2) ? wsu_h : wsg_h;
        __builtin_amdgcn_global_load_lds(
            (const __attribute__((address_space(1))) void*)
                ((const char*)src + bByte[i] + kt * 128),
            (__attribute__((address_space(3))) void*)&sB[buf][(tid + i * 256) * 8],
            16, 0, 0);
      }
    };
    auto computeTile = [&](int ia, int ib) {
      const char* pA = (const char*)&sA[ia][0];
      const char* pB = (const char*)&sB[ib][0];
#pragma unroll
      for (int kk = 0; kk < 2; ++kk) {
        const int koff = kk * 32 + (lane >> 4) * 8;
        half8 a[4];
#pragma unroll
        for (int m = 0; m < 4; ++m) {
          int r = wr * 64 + m * 16 + (lane & 15);
          int byt = ((r << 7) + (koff << 1)) ^ ((r & 7) << 4);
          a[m] = *(const half8*)(pA + byt);
        }
        half8 bg[2], bu[2];
#pragma unroll
        for (int n = 0; n < 2; ++n) {
          int rn = wc * 32 + n * 16 + (lane & 15);
          int byt = ((rn << 7) + (koff << 1)) ^ ((rn & 7) << 4);
          bg[n] = *(const half8*)(pB + byt);
          bu[n] = *(const half8*)(pB + 8192 + byt);
        }
#pragma unroll
        for (int m = 0; m < 4; ++m)
#pragma unroll
          for (int n = 0; n < 2; ++n) {
            accG[m][n] = __builtin_amdgcn_mfma_f32_16x16x32_f16(a[m], bg[n], accG[m][n], 0, 0, 0);
            accU[m][n] = __builtin_amdgcn_mfma_f32_16x16x32_f16(a[m], bu[n], accU[m][n], 0, 0, 0);
          }
      }
    };

    stageB(0, 0);
    __builtin_amdgcn_sched_barrier(0);
    stageA(0, 0);
    __builtin_amdgcn_sched_barrier(0);
    stageA(1, 1);
    __builtin_amdgcn_sched_barrier(0);

    int bufC = 0, bufW = 2;
    for (int kt = 0; kt < KT; ++kt) {
      asm volatile("s_waitcnt lgkmcnt(0)" ::: "memory");
      if (kt + 1 < KT) { asm volatile("s_waitcnt vmcnt(4)" ::: "memory"); }
      else             { asm volatile("s_waitcnt vmcnt(0)" ::: "memory"); }
      __builtin_amdgcn_sched_barrier(0);
      __builtin_amdgcn_s_barrier();
      __builtin_amdgcn_sched_barrier(0);
      if (kt + 1 < KT) stageB(kt + 1, (kt + 1) & 1);
      if (kt + 2 < KT) stageA(kt + 2, bufW);
      __builtin_amdgcn_sched_barrier(0);
      computeTile(bufC, kt & 1);
      bufC = (bufC == 2) ? 0 : bufC + 1;
      bufW = (bufW == 2) ? 0 : bufW + 1;
    }

#pragma unroll
    for (int m = 0; m < 4; ++m)
#pragma unroll
      for (int i = 0; i < 4; ++i) {
        int row = rowBase + wr * 64 + m * 16 + (lane >> 4) * 4 + i;
#pragma unroll
        for (int n = 0; n < 2; ++n) {
          int col = nBase + wc * 32 + n * 16 + (lane & 15);
          float gv = accG[m][n][i];
          float uv = accU[m][n][i];
          Hsh[(long long)row * DSH + col] =
              (_Float16)((gv / (1.f + __expf(-gv))) * uv);
        }
      }
    return;
  }

  // ---------------- region 0: routed gate+up, fused dequant (r7) ----------
  {
    constexpr int KT = DD / 64;               // 32
    constexpr int BCH = 4;
    const int f = bid;
    const int xcd = f & 7;
    const int t0 = f >> 3;
    const int mb = t0 % 8;
    const int pp = t0 / 8;
    const int p  = pp * 8 + xcd;              // [0,384)
    const int nb = p % 12;
    const int e  = p / 12;

    int rows = cnt[e] > CAP ? CAP : cnt[e];
    const int rowBase = mb * 128;
    if (rowBase >= rows) return;
    const int nBase = nb * 64;

    const float* B0e = wg + (long long)e * DFF * DD;
    const float* B1e = wu + (long long)e * DFF * DD;
    const float* S0e = sg + (long long)e * ((DFF / 128) * (DD / 128));
    const float* S1e = su + (long long)e * ((DFF / 128) * (DD / 128));
    const int sRow = (nBase >> 7) * (DD / 128);

    int aByte[4];
#pragma unroll
    for (int i = 0; i < 4; ++i) {
      int c = tid + i * 256;
      int row = c >> 3;
      int colB = ((c & 7) << 4) ^ ((row & 7) << 4);
      int src = slot_tok[e * CAP + rowBase + row];
      aByte[i] = src * (2 * DD) + colB;
    }
    int bOff[BCH], wByte[BCH];
#pragma unroll
    for (int i = 0; i < BCH; ++i) {
      int c = tid + i * 256;
      int rn = c >> 4;
      int c4 = (c & 15) << 2;
      bOff[i] = (nBase + rn) * DD + c4;
      wByte[i] = ((rn << 7) + (c4 << 1)) ^ ((rn & 7) << 4);
    }

    f32x4 accG[4][2], accU[4][2];
#pragma unroll
    for (int m = 0; m < 4; ++m)
#pragma unroll
      for (int n = 0; n < 2; ++n) {
        accG[m][n] = (f32x4){0.f, 0.f, 0.f, 0.f};
        accU[m][n] = (f32x4){0.f, 0.f, 0.f, 0.f};
      }

    auto stageA = [&](int kt, int buf) {
#pragma unroll
      for (int i = 0; i < 4; ++i) {
        __builtin_amdgcn_global_load_lds(
            (const __attribute__((address_space(1))) void*)
                ((const char*)x_h + aByte[i] + kt * 128),
            (__attribute__((address_space(3))) void*)&sA[buf][(tid + i * 256) * 8],
            16, 0, 0);
      }
    };
    auto loadB = [&](int kt, float4 (&r0)[BCH], float4 (&r1)[BCH]) {
      const int ko = kt * 64;
#pragma unroll
      for (int i = 0; i < BCH; ++i) r0[i] = *(const float4*)(B0e + bOff[i] + ko);
#pragma unroll
      for (int i = 0; i < BCH; ++i) r1[i] = *(const float4*)(B1e + bOff[i] + ko);
    };
    auto storeB = [&](int kt, float4 (&r0)[BCH], float4 (&r1)[BCH]) {
      float s0 = S0e[sRow + (kt >> 1)];
      float s1 = S1e[sRow + (kt >> 1)];
      char* base = (char*)&sB[kt & 1][0];
#pragma unroll
      for (int i = 0; i < BCH; ++i) {
        half4v h = { (_Float16)(r0[i].x * s0), (_Float16)(r0[i].y * s0),
                     (_Float16)(r0[i].z * s0), (_Float16)(r0[i].w * s0) };
        *(half4v*)(base + wByte[i]) = h;
        half4v h1 = { (_Float16)(r1[i].x * s1), (_Float16)(r1[i].y * s1),
                      (_Float16)(r1[i].z * s1), (_Float16)(r1[i].w * s1) };
        *(half4v*)(base + 8192 + wByte[i]) = h1;
      }
    };
    auto computeTile = [&](int ia, int ib) {
      const char* pA = (const char*)&sA[ia][0];
      const char* pB = (const char*)&sB[ib][0];
#pragma unroll
      for (int kk = 0; kk < 2; ++kk) {
        const int koff = kk * 32 + (lane >> 4) * 8;
        half8 a[4];
#pragma unroll
        for (int m = 0; m < 4; ++m) {
          int r = wr * 64 + m * 16 + (lane & 15);
          int byt = ((r << 7) + (koff << 1)) ^ ((r & 7) << 4);
          a[m] = *(const half8*)(pA + byt);
        }
        half8 bg[2], bu[2];
#pragma unroll
        for (int n = 0; n < 2; ++n) {
          int rn = wc * 32 + n * 16 + (lane & 15);
          int byt = ((rn << 7) + (koff << 1)) ^ ((rn & 7) << 4);
          bg[n] = *(const half8*)(pB + byt);
          bu[n] = *(const half8*)(pB + 8192 + byt);
        }
#pragma unroll
        for (int m = 0; m < 4; ++m)
#pragma unroll
          for (int n = 0; n < 2; ++n) {
            accG[m][n] = __builtin_amdgcn_mfma_f32_16x16x32_f16(a[m], bg[n], accG[m][n], 0, 0, 0);
            accU[m][n] = __builtin_amdgcn_mfma_f32_16x16x32_f16(a[m], bu[n], accU[m][n], 0, 0, 0);
          }
      }
    };

    float4 rbE0[BCH], rbE1[BCH], rbO0[BCH], rbO1[BCH];

    stageA(0, 0); loadB(0, rbE0, rbE1);
    __builtin_amdgcn_sched_barrier(0);
    stageA(1, 1); loadB(1, rbO0, rbO1);
    __builtin_amdgcn_sched_barrier(0);

    int bufC = 0, bufW = 2;
    for (int kt = 0; kt < KT; kt += 2) {
      if (kt + 1 < KT) { asm volatile("s_waitcnt vmcnt(12)" ::: "memory"); }
      else             { asm volatile("s_waitcnt vmcnt(0)"  ::: "memory"); }
      __builtin_amdgcn_sched_barrier(0);
      storeB(kt, rbE0, rbE1);
      asm volatile("s_waitcnt lgkmcnt(0)" ::: "memory");
      __builtin_amdgcn_sched_barrier(0);
      __builtin_amdgcn_s_barrier();
      __builtin_amdgcn_sched_barrier(0);
      if (kt + 2 < KT) { stageA(kt + 2, bufW); loadB(kt + 2, rbE0, rbE1); }
      __builtin_amdgcn_sched_barrier(0);
      computeTile(bufC, 0);
      bufC = (bufC == 2) ? 0 : bufC + 1;
      bufW = (bufW == 2) ? 0 : bufW + 1;

      if (kt + 2 < KT) { asm volatile("s_waitcnt vmcnt(12)" ::: "memory"); }
      else             { asm volatile("s_waitcnt vmcnt(0)"  ::: "memory"); }
      __builtin_amdgcn_sched_barrier(0);
      storeB(kt + 1, rbO0, rbO1);
      asm volatile("s_waitcnt lgkmcnt(0)" ::: "memory");
      __builtin_amdgcn_sched_barrier(0);
      __builtin_amdgcn_s_barrier();
      __builtin_amdgcn_sched_barrier(0);
      if (kt + 3 < KT) { stageA(kt + 3, bufW); loadB(kt + 3, rbO0, rbO1); }
      __builtin_amdgcn_sched_barrier(0);
      computeTile(bufC, 1);
      bufC = (bufC == 2) ? 0 : bufC + 1;
      bufW = (bufW == 2) ? 0 : bufW + 1;
    }

#pragma unroll
    for (int m = 0; m < 4; ++m)
#pragma unroll
      for (int i = 0; i < 4; ++i) {
        int row = rowBase + wr * 64 + m * 16 + (lane >> 4) * 4 + i;
        if (row < rows) {
#pragma unroll
          for (int n = 0; n < 2; ++n) {
            int col = nBase + wc * 32 + n * 16 + (lane & 15);
            float gv = accG[m][n][i];
            float uv = accU[m][n][i];
            H[(long long)e * CAP * DFF + (long long)row * DFF + col] =
                (_Float16)((gv / (1.f + __expf(-gv))) * uv);
          }
        }
      }
  }
}

// ===================== MEGA-B ==============================================
// [0,4096)  routed down, clean DMA f16  -> Yp (scatter w*val by pair)
// [4096,4352) shared down, clean DMA    -> Ysh
__global__ __launch_bounds__(256, 2) void k_megaB(
    const _Float16* __restrict__ H, const _Float16* __restrict__ wd_h,
    _Float16* __restrict__ Yp,
    const int* __restrict__ cnt,
    const int* __restrict__ slot_pair, const float* __restrict__ slot_w,
    const _Float16* __restrict__ Hsh, const _Float16* __restrict__ wsd_h,
    _Float16* __restrict__ Ysh) {
  __shared__ __align__(16) _Float16 sA[3][8192];
  __shared__ __align__(16) _Float16 sB[2][8192];

  const int tid = threadIdx.x;
  const int bid = blockIdx.x;
  const int lane = tid & 63;
  const int wave = tid >> 6;
  const int wr = wave >> 1;
  const int wc = wave & 1;

  // region decode (block-uniform)
  const _Float16 *Ab, *Bb;
  _Float16* Outp;
  int KDIM, KT, rows, ldA, e = 0, nb, mb;
  bool scatter;
  if (bid < 4096) {
    int xcd = bid & 7, t0 = bid >> 3;
    mb = t0 % 8;
    int pp = t0 / 8;
    int p = pp * 8 + xcd;                     // [0,512)
    nb = p % 16;
    e = p / 16;
    rows = cnt[e] > CAP ? CAP : cnt[e];
    scatter = true;
    Ab = H + (long long)e * CAP * DFF;
    Bb = wd_h + (long long)e * DD * DFF;
    KDIM = DFF; KT = DFF / 64; ldA = DFF;     // KT=12
    Outp = Yp;
  } else {
    int f2 = bid - 4096;
    int xcd = f2 & 7, t0 = f2 >> 3;
    mb = t0 % 16;
    int pp = t0 / 16;
    int p = pp * 8 + xcd;                     // [0,16)
    nb = p % 16;
    rows = TT;
    scatter = false;
    Ab = Hsh;
    Bb = wsd_h;
    KDIM = DSH; KT = DSH / 64; ldA = DSH;     // KT=32
    Outp = Ysh;
  }
  const int rowBase = mb * 128;
  if (rowBase >= rows) return;
  const int nBase = nb * 128;

  int aByte[4];
#pragma unroll
  for (int i = 0; i < 4; ++i) {
    int c = tid + i * 256;
    int row = c >> 3;
    int colB = ((c & 7) << 4) ^ ((row & 7) << 4);
    aByte[i] = (rowBase + row) * (2 * ldA) + colB;
  }
  int bByte[4];
#pragma unroll
  for (int i = 0; i < 4; ++i) {
    int c = tid + i * 256;
    int rn = c >> 3;                          // [0,128)
    int colB = ((c & 7) << 4) ^ ((rn & 7) << 4);
    bByte[i] = (nBase + rn) * (2 * KDIM) + colB;
  }

  f32x4 acc[4][4];
#pragma unroll
  for (int m = 0; m < 4; ++m)
#pragma unroll
    for (int n = 0; n < 4; ++n) acc[m][n] = (f32x4){0.f, 0.f, 0.f, 0.f};

  auto stageA = [&](int kt, int buf) {
#pragma unroll
    for (int i = 0; i < 4; ++i) {
      __builtin_amdgcn_global_load_lds(
          (const __attribute__((address_space(1))) void*)
              ((const char*)Ab + aByte[i] + kt * 128),
          (__attribute__((address_space(3))) void*)&sA[buf][(tid + i * 256) * 8],
          16, 0, 0);
    }
  };
  auto stageB = [&](int kt, int buf) {
#pragma unroll
    for (int i = 0; i < 4; ++i) {
      __builtin_amdgcn_global_load_lds(
          (const __attribute__((address_space(1))) void*)
              ((const char*)Bb + bByte[i] + kt * 128),
          (__attribute__((address_space(3))) void*)&sB[buf][(tid + i * 256) * 8],
          16, 0, 0);
    }
  };
  auto computeTile = [&](int ia, int ib) {
    const char* pA = (const char*)&sA[ia][0];
    const char* pB = (const char*)&sB[ib][0];
#pragma unroll
    for (int kk = 0; kk < 2; ++kk) {
      const int koff = kk * 32 + (lane >> 4) * 8;
      half8 a[4];
#pragma unroll
      for (int m = 0; m < 4; ++m) {
        int r = wr * 64 + m * 16 + (lane & 15);
        int byt = ((r << 7) + (koff << 1)) ^ ((r & 7) << 4);
        a[m] = *(const half8*)(pA + byt);
      }
      half8 b[4];
#pragma unroll
      for (int n = 0; n < 4; ++n) {
        int rn = wc * 64 + n * 16 + (lane & 15);
        int byt = ((rn << 7) + (koff << 1)) ^ ((rn & 7) << 4);
        b[n] = *(const half8*)(pB + byt);
      }
#pragma unroll
      for (int m = 0; m < 4; ++m)
#pragma unroll
        for (int n = 0; n < 4; ++n)
          acc[m][n] = __builtin_amdgcn_mfma_f32_16x16x32_f16(a[m], b[n], acc[m][n], 0, 0, 0);
    }
  };

  stageB(0, 0);
  __builtin_amdgcn_sched_barrier(0);
  stageA(0, 0);
  __builtin_amdgcn_sched_barrier(0);
  stageA(1, 1);
  __builtin_amdgcn_sched_barrier(0);

  int bufC = 0, bufW = 2;
  for (int kt = 0; kt < KT; ++kt) {
    asm volatile("s_waitcnt lgkmcnt(0)" ::: "memory");
    if (kt + 1 < KT) { asm volatile("s_waitcnt vmcnt(4)" ::: "memory"); }
    else             { asm volatile("s_waitcnt vmcnt(0)" ::: "memory"); }
    __builtin_amdgcn_sched_barrier(0);
    __builtin_amdgcn_s_barrier();
    __builtin_amdgcn_sched_barrier(0);
    if (kt + 1 < KT) stageB(kt + 1, (kt + 1) & 1);
    if (kt + 2 < KT) stageA(kt + 2, bufW);
    __builtin_amdgcn_sched_barrier(0);
    computeTile(bufC, kt & 1);
    bufC = (bufC == 2) ? 0 : bufC + 1;
    bufW = (bufW == 2) ? 0 : bufW + 1;
  }

#pragma unroll
  for (int m = 0; m < 4; ++m)
#pragma unroll
    for (int i = 0; i < 4; ++i) {
      int row = rowBase + wr * 64 + m * 16 + (lane >> 4) * 4 + i;
      if (row < rows) {
        if (scatter) {
          int pair = slot_pair[e * CAP + row];
          float w = slot_w[e * CAP + row];
#pragma unroll
          for (int n = 0; n < 4; ++n) {
            int col = nBase + wc * 64 + n * 16 + (lane & 15);
            Outp[(long long)pair * DD + col] = (_Float16)(w * acc[m][n][i]);
          }
        } else {
#pragma unroll
          for (int n = 0; n < 4; ++n) {
            int col = nBase + wc * 64 + n * 16 + (lane & 15);
            Outp[(long long)row * DD + col] = (_Float16)acc[m][n][i];
          }
        }
      }
    }
}

// ---------------- combine2: out = sum_k keep*Yp + shg*Ysh -------------------
__global__ __launch_bounds__(256) void k_combine2(
    const _Float16* __restrict__ Yp, const _Float16* __restrict__ Ysh,
    const float* __restrict__ shg, const int* __restrict__ pair_pos,
    float* __restrict__ out) {
  int t = blockIdx.x;
  int col = threadIdx.x * 8;
  float acc[8];
  half8 ys = *(const half8*)&Ysh[(size_t)t * DD + col];
  float g = shg[t];
#pragma unroll
  for (int j = 0; j < 8; ++j) acc[j] = g * (float)ys[j];
#pragma unroll
  for (int k = 0; k < KTOP; ++k) {
    if (pair_pos[t * KTOP + k] < CAP) {
      half8 y = *(const half8*)&Yp[((size_t)t * KTOP + k) * DD + col];
#pragma unroll
      for (int j = 0; j < 8; ++j) acc[j] += (float)y[j];
    }
  }
  float4 o0 = {acc[0], acc[1], acc[2], acc[3]};
  float4 o1 = {acc[4], acc[5], acc[6], acc[7]};
  *(float4*)&out[(size_t)t * DD + col] = o0;
  *(float4*)&out[(size_t)t * DD + col + 4] = o1;
}

// ---------------------------------------------------------------------------
extern "C" void kernel_launch(void* const* d_in, const int* in_sizes, int n_in,
                              void* d_out, int out_size, void* d_ws, size_t ws_size,
                              hipStream_t stream) {
  (void)in_sizes; (void)n_in; (void)out_size; (void)ws_size;
  const float* x    = (const float*)d_in[0];
  const float* rw   = (const float*)d_in[1];
  const float* wg   = (const float*)d_in[2];
  const float* sg   = (const float*)d_in[3];
  const float* wu   = (const float*)d_in[4];
  const float* su   = (const float*)d_in[5];
  const float* wd   = (const float*)d_in[6];
  const float* sd   = (const float*)d_in[7];
  const float* wsg  = (const float*)d_in[8];
  const float* wsu  = (const float*)d_in[9];
  const float* wsd  = (const float*)d_in[10];
  const float* wshg = (const float*)d_in[11];
  float* out = (float*)d_out;

  // workspace ~261 MB (Ysh aliases wsg_h, dead after MEGA-A)
  char* p = (char*)d_ws;
  auto alloc = [&](size_t bytes) {
    char* r = p;
    p += (bytes + 255) & ~(size_t)255;
    return r;
  };
  _Float16* x_h   = (_Float16*)alloc((size_t)TT * DD * 2);          //   8.4 MB
  _Float16* H     = (_Float16*)alloc((size_t)EE * CAP * DFF * 2);   //  50.3 MB
  _Float16* Hsh   = (_Float16*)alloc((size_t)TT * DSH * 2);         //   8.4 MB
  _Float16* Yp    = (_Float16*)alloc((size_t)TT * KTOP * DD * 2);   //  67.1 MB
  _Float16* wd_h  = (_Float16*)alloc((size_t)EE * DD * DFF * 2);    // 100.7 MB
  _Float16* wsg_h = (_Float16*)alloc((size_t)DSH * DD * 2);         //   8.4 MB
  _Float16* wsu_h = (_Float16*)alloc((size_t)DSH * DD * 2);         //   8.4 MB
  _Float16* wsd_h = (_Float16*)alloc((size_t)DD * DSH * 2);         //   8.4 MB
  float* shg      = (float*)alloc((size_t)TT * 4);
  int* cnt        = (int*)alloc((size_t)EE * 4);
  int* slot_tok   = (int*)alloc((size_t)EE * CAP * 4);
  float* slot_w   = (float*)alloc((size_t)EE * CAP * 4);
  int* slot_pair  = (int*)alloc((size_t)EE * CAP * 4);
  int* pair_pos   = (int*)alloc((size_t)TT * KTOP * 4);

  _Float16* Ysh = wsg_h;   // alias: wsg_h dead after MEGA-A; Ysh written in MEGA-B

  k_init<<<(EE * CAP + 255) / 256, 256, 0, stream>>>(cnt, slot_tok);
  k_cast<<<(TT * DD / 4) / 256, 256, 0, stream>>>(x, x_h);
  k_cast<<<(DSH * DD / 4) / 256, 256, 0, stream>>>(wsg, wsg_h);
  k_cast<<<(DSH * DD / 4) / 256, 256, 0, stream>>>(wsu, wsu_h);
  k_cast<<<(DD * DSH / 4) / 256, 256, 0, stream>>>(wsd, wsd_h);
  k_router<<<TT, 64, 0, stream>>>(x, rw, wshg, shg, cnt, slot_tok, slot_w,
                                  slot_pair, pair_pos);

  // MEGA-A: routed gate+up | shared gate+up | wd dequant stream
  k_megaA<<<4096, 256, 0, stream>>>(x_h, wg, wu, sg, su, H, cnt, slot_tok,
                                    wsg_h, wsu_h, Hsh, wd, sd, wd_h);

  // MEGA-B: routed down (clean f16) | shared down -> Ysh
  k_megaB<<<4352, 256, 0, stream>>>(H, wd_h, Yp, cnt, slot_pair, slot_w,
                                    Hsh, wsd_h, Ysh);

  // combine: out = sum_k keep*Yp + shg*Ysh
  k_combine2<<<TT, 256, 0, stream>>>(Yp, Ysh, shg, pair_pos, out);
}